// Round 3
// baseline (350.596 us; speedup 1.0000x reference)
//
#include <hip/hip_runtime.h>
#include <hip/hip_fp16.h>

#define BKN 4        // nodes per fine bucket (per hop wave)
#define CBN 256      // nodes per coarse bin
#define CHUNK 4096   // edges per passA/histCB block
#define MAXBIN 5120  // max edges per coarse bin (mean 4096, sd 64)

typedef _Float16 half8 __attribute__((ext_vector_type(8)));
typedef float floatx4 __attribute__((ext_vector_type(4)));

// ---------------- zero ----------------

__global__ void zero_int_kernel(int* __restrict__ p, int n) {
    int i = blockIdx.x * blockDim.x + threadIdx.x;
    if (i < n) p[i] = 0;
}

// ---------------- histCB: coarse-bin histogram with LDS pre-aggregation ----------------

__global__ __launch_bounds__(256) void histCB_kernel(const int* __restrict__ ei,
                                                     int* __restrict__ cntCB,
                                                     int E, int NCB) {
    __shared__ int lcnt[512];
    int tid = threadIdx.x;
    for (int i = tid; i < 512; i += 256) lcnt[i] = 0;
    __syncthreads();
    int base = blockIdx.x * CHUNK;
    #pragma unroll
    for (int q = 0; q < 16; ++q) {
        int e = base + q * 256 + tid;
        if (e < E) atomicAdd(&lcnt[ei[E + e] >> 8], 1);
    }
    __syncthreads();
    for (int i = tid; i < NCB; i += 256)
        if (lcnt[i]) atomicAdd(&cntCB[i], lcnt[i]);
}

// ---------------- scanCB: single-block scan of coarse counts ----------------

__global__ __launch_bounds__(512) void scanCB_kernel(const int* __restrict__ cntCB,
                                                     int* __restrict__ offCB,
                                                     int* __restrict__ curCB, int NCB) {
    __shared__ int sA[512], sB[512];
    int tid = threadIdx.x;
    sA[tid] = (tid < NCB) ? cntCB[tid] : 0;
    __syncthreads();
    int* src = sA; int* dst = sB;
    for (int o = 1; o < 512; o <<= 1) {
        dst[tid] = src[tid] + (tid >= o ? src[tid - o] : 0);
        __syncthreads();
        int* t = src; src = dst; dst = t;
    }
    if (tid <= NCB) {
        int v = (tid > 0) ? src[tid - 1] : 0;
        offCB[tid] = v;
        if (tid < NCB) curCB[tid] = v;
    }
}

// ---------------- passA: multisplit edges into coarse bins ----------------
// packed: (r<<8) | (c & 255)

__global__ __launch_bounds__(256) void passA_kernel(const int* __restrict__ ei,
                                                    int* __restrict__ curCB,
                                                    unsigned* __restrict__ binned,
                                                    int E, int NCB) {
    __shared__ int lcnt[512];
    __shared__ int sA[512], sB[512];
    __shared__ int loffx[512];
    __shared__ int gbase[512];
    __shared__ int lpos[512];
    __shared__ unsigned stage[CHUNK];
    int tid = threadIdx.x;
    int base = blockIdx.x * CHUNK;
    for (int i = tid; i < 512; i += 256) lcnt[i] = 0;
    __syncthreads();
    unsigned pk[16]; int bin[16];
    #pragma unroll
    for (int q = 0; q < 16; ++q) {
        int e = base + q * 256 + tid;
        if (e < E) {
            int r = ei[e], c = ei[E + e];
            pk[q] = ((unsigned)r << 8) | (unsigned)(c & 255);
            bin[q] = c >> 8;
            atomicAdd(&lcnt[bin[q]], 1);
        } else bin[q] = -1;
    }
    __syncthreads();
    for (int i = tid; i < 512; i += 256) sA[i] = lcnt[i];
    __syncthreads();
    int* src = sA; int* dst = sB;
    for (int o = 1; o < 512; o <<= 1) {
        for (int i = tid; i < 512; i += 256)
            dst[i] = src[i] + (i >= o ? src[i - o] : 0);
        __syncthreads();
        int* t = src; src = dst; dst = t;
    }
    for (int i = tid; i < 512; i += 256) {
        int ex = (i > 0) ? src[i - 1] : 0;
        loffx[i] = ex;
        lpos[i] = ex;
        int c = lcnt[i];
        gbase[i] = (c > 0 && i < NCB) ? atomicAdd(&curCB[i], c) : 0;
    }
    __syncthreads();
    #pragma unroll
    for (int q = 0; q < 16; ++q) {
        if (bin[q] >= 0) {
            int p = atomicAdd(&lpos[bin[q]], 1);
            stage[p] = pk[q];
        }
    }
    __syncthreads();
    for (int b = tid; b < NCB; b += 256) {
        int n = lcnt[b];
        int g = gbase[b];
        int lo = loffx[b];
        for (int i2 = 0; i2 < n; ++i2) binned[g + i2] = stage[lo + i2];
    }
}

// ---------------- passB: fine-sort within coarse bin; emit bkt, offB, dinv -------
// bkt word: (r<<2) | (c&3)

__global__ __launch_bounds__(256) void passB_kernel(const unsigned* __restrict__ binned,
                                                    const int* __restrict__ offCB,
                                                    unsigned* __restrict__ bkt,
                                                    int* __restrict__ offB,
                                                    float* __restrict__ dinv,
                                                    int N, int NCB, int NB) {
    __shared__ unsigned raw[MAXBIN];
    __shared__ unsigned stage[MAXBIN];
    __shared__ int fcnt[64], foff[65], fpos[64];
    __shared__ int ncnt[256];
    int i = blockIdx.x;
    int tid = threadIdx.x;
    int g0 = offCB[i], g1 = offCB[i + 1];
    int cnt = g1 - g0;
    if (cnt > MAXBIN) cnt = MAXBIN;  // safety (statistically unreachable)
    for (int j = tid; j < 64; j += 256) fcnt[j] = 0;
    ncnt[tid] = 0;
    __syncthreads();
    for (int idx = tid; idx < cnt; idx += 256) {
        unsigned pk = binned[g0 + idx];
        raw[idx] = pk;
        atomicAdd(&fcnt[(pk >> 2) & 63], 1);
        atomicAdd(&ncnt[pk & 255], 1);
    }
    __syncthreads();
    if (tid == 0) {
        int run = 0;
        for (int j = 0; j < 64; ++j) { foff[j] = run; run += fcnt[j]; }
        foff[64] = run;
    }
    __syncthreads();
    if (tid < 64) fpos[tid] = foff[tid];
    __syncthreads();
    for (int idx = tid; idx < cnt; idx += 256) {
        unsigned pk = raw[idx];
        int p = atomicAdd(&fpos[(pk >> 2) & 63], 1);
        stage[p] = ((pk >> 8) << 2) | (pk & 3);
    }
    __syncthreads();
    for (int idx = tid; idx < cnt; idx += 256) bkt[g0 + idx] = stage[idx];
    int fb0 = i * 64;
    int nfb = min(64, NB - fb0);
    for (int j = tid; j < nfb; j += 256) offB[fb0 + j] = g0 + foff[j];
    if (i == NCB - 1 && tid == 0) offB[NB] = g1;
    int n0 = i * CBN;
    int n = n0 + tid;
    if (n < N) dinv[n] = rsqrtf((float)ncnt[tid] + 1.0f);
}

// ---------------- weight folding ----------------
// Wf1 = W1*(W3top*W4) [64x64], Wf2 = W2*(W3bot*W4) [32x64]
// u = (b12*W3)*W4 [64], v = b3*W4 [64]
// 256 threads (known-good launch shape): q = tid>>6 in [0,4), f = tid&63.
// W4 staged in LDS once (row-broadcast reads = 2-way alias = free);
// W3/W1/W2 reads are wave-uniform (same q across a wave) -> scalar loads.
// This removes the per-FMA global-load latency chain that made this kernel
// 56us at VALUBusy=0.05% (5x top dispatch in round-0 profile).
__global__ __launch_bounds__(256) void fold_kernel(
    const float* __restrict__ W1, const float* __restrict__ b1,
    const float* __restrict__ W2, const float* __restrict__ b2,
    const float* __restrict__ W3, const float* __restrict__ b3,
    const float* __restrict__ W4,
    float* __restrict__ Wf1, float* __restrict__ Wf2,
    float* __restrict__ u, float* __restrict__ v) {
    __shared__ float A1[64][64];
    __shared__ float A2[64][64];
    __shared__ float W4s[64][64];
    __shared__ float gs[64];
    int tid = threadIdx.x;
    int q = tid >> 6;
    int f = tid & 63;
    // stage W4 (64x64 f32) coalesced: 16 fixed iterations
    #pragma unroll
    for (int it = 0; it < 16; ++it) {
        int i = it * 256 + tid;
        W4s[i >> 6][i & 63] = W4[i];
    }
    __syncthreads();
    // phase 1: A1 = W3top @ W4, A2 = W3bot @ W4  (16 rows per q-group)
    for (int i = q * 16; i < q * 16 + 16; ++i) {
        float a1 = 0.f, a2 = 0.f;
        #pragma unroll
        for (int k = 0; k < 64; ++k) {
            float w4 = W4s[k][f];
            a1 += W3[i * 64 + k] * w4;        // uniform -> s_load
            a2 += W3[(64 + i) * 64 + k] * w4;
        }
        A1[i][f] = a1;
        A2[i][f] = a2;
    }
    if (q == 0) {
        float g = 0.f;
        for (int k = 0; k < 64; ++k) g += b1[k] * W3[k * 64 + f];
        for (int k = 0; k < 64; ++k) g += b2[k] * W3[(64 + k) * 64 + f];
        gs[f] = g;
    }
    __syncthreads();
    // phase 2: Wf1 = W1 @ A1 (16 rows/q), Wf2 = W2 @ A2 (8 rows/q)
    for (int i = q * 16; i < q * 16 + 16; ++i) {
        float a = 0.f;
        #pragma unroll
        for (int k = 0; k < 64; ++k) a += W1[i * 64 + k] * A1[k][f];
        Wf1[i * 64 + f] = a;
    }
    for (int i = q * 8; i < q * 8 + 8; ++i) {
        float a = 0.f;
        #pragma unroll
        for (int k = 0; k < 64; ++k) a += W2[i * 64 + k] * A2[k][f];
        Wf2[i * 64 + f] = a;
    }
    if (q == 0) {
        float uu = 0.f, vv = 0.f;
        #pragma unroll
        for (int k = 0; k < 64; ++k) {
            float w4 = W4s[k][f];
            uu += gs[k] * w4;
            vv += b3[k] * w4;
        }
        u[f] = uu;
        v[f] = vv;
    }
}

// ---------------- linZ via MFMA: Z[n] = fp16( (X~[n] @ Wf) * dinv[n] ) ----------------
// X~ = [lat | cond] (96 wide), Wf = [Wf1; Wf2] (96x64).
// Block = 64 nodes. LDS: Xs[64][104] fp16, Wt[64][104] fp16 (f-major, k inner).
// Wave w computes M-tile w (16 nodes) x all 64 feats via 3 K-chunks x 4 N-tiles MFMA.
// Layouts (verified): A[m=lane&15][k=quad*8+j]; B[n=lane&15][k=quad*8+j];
//                     C/D col=lane&15, row=quad*4+reg.
__global__ __launch_bounds__(256) void linZ_kernel(
    const float* __restrict__ lat, const float* __restrict__ cond,
    const float* __restrict__ Wf1, const float* __restrict__ Wf2,
    const float* __restrict__ dinv, _Float16* __restrict__ Z, int N) {
    __shared__ _Float16 Xs[64][104];   // pad 96->104: b128 frag reads 2-way only
    __shared__ _Float16 Wt[64][104];
    int tid = threadIdx.x;
    int n0 = blockIdx.x * 64;
    // stage lat (64x64 fp32 -> fp16), coalesced float4
    {
        const float4* lat4 = (const float4*)(lat + (size_t)n0 * 64);
        #pragma unroll
        for (int q = 0; q < 4; ++q) {
            int idx = q * 256 + tid;            // 1024 float4, 16 per row
            int row = idx >> 4;
            float4 v = make_float4(0.f, 0.f, 0.f, 0.f);
            if (n0 + row < N) v = lat4[idx];
            int col = (idx & 15) * 4;
            Xs[row][col + 0] = (_Float16)v.x;
            Xs[row][col + 1] = (_Float16)v.y;
            Xs[row][col + 2] = (_Float16)v.z;
            Xs[row][col + 3] = (_Float16)v.w;
        }
        const float4* cond4 = (const float4*)(cond + (size_t)n0 * 32);
        #pragma unroll
        for (int q = 0; q < 2; ++q) {
            int idx = q * 256 + tid;            // 512 float4, 8 per row
            int row = idx >> 3;
            float4 v = make_float4(0.f, 0.f, 0.f, 0.f);
            if (n0 + row < N) v = cond4[idx];
            int col = 64 + (idx & 7) * 4;
            Xs[row][col + 0] = (_Float16)v.x;
            Xs[row][col + 1] = (_Float16)v.y;
            Xs[row][col + 2] = (_Float16)v.z;
            Xs[row][col + 3] = (_Float16)v.w;
        }
        // stage W transposed: Wt[f][k]
        for (int i = tid; i < 4096; i += 256) {
            int k = i >> 6, f = i & 63;
            Wt[f][k] = (_Float16)Wf1[i];
        }
        for (int i = tid; i < 2048; i += 256) {
            int k = i >> 6, f = i & 63;
            Wt[f][64 + k] = (_Float16)Wf2[i];
        }
    }
    __syncthreads();
    int lane = tid & 63, wave = tid >> 6;
    int quad = lane >> 4, l16 = lane & 15;
    floatx4 acc[4] = {};
    #pragma unroll
    for (int kc = 0; kc < 96; kc += 32) {
        half8 a = *(const half8*)&Xs[wave * 16 + l16][kc + quad * 8];
        #pragma unroll
        for (int nt = 0; nt < 4; ++nt) {
            half8 b = *(const half8*)&Wt[nt * 16 + l16][kc + quad * 8];
            acc[nt] = __builtin_amdgcn_mfma_f32_16x16x32_f16(a, b, acc[nt], 0, 0, 0);
        }
    }
    #pragma unroll
    for (int r = 0; r < 4; ++r) {
        int n = n0 + wave * 16 + quad * 4 + r;
        if (n < N) {
            float d = dinv[n];
            #pragma unroll
            for (int nt = 0; nt < 4; ++nt)
                Z[(size_t)n * 64 + nt * 16 + l16] = (_Float16)(acc[nt][r] * d);
        }
    }
}

// ---------------- hop: wave per 4-node bucket, register accumulate, fp16 rows ------
// Vp = fp16( dinv ⊙ true features )
// FINAL=false: out16[c] = fp16( acc*d^2 + d*wvec[f] )
// FINAL=true : out32[c] = acc*d + wvec[f]
template <bool FINAL>
__global__ __launch_bounds__(256) void hop_kernel(
    const _Float16* __restrict__ Vp, const float* __restrict__ dinv,
    const int* __restrict__ offB, const unsigned* __restrict__ bkt,
    const float* __restrict__ wvec, void* __restrict__ outv, int NB) {
    int lane = threadIdx.x & 63;
    int wave = threadIdx.x >> 6;
    int b = blockIdx.x * 4 + wave;
    if (b >= NB) return;
    int c0 = b * BKN;
    float acc0 = (float)Vp[(size_t)(c0 + 0) * 64 + lane];
    float acc1 = (float)Vp[(size_t)(c0 + 1) * 64 + lane];
    float acc2 = (float)Vp[(size_t)(c0 + 2) * 64 + lane];
    float acc3 = (float)Vp[(size_t)(c0 + 3) * 64 + lane];
    int s = offB[b], e = offB[b + 1];
    for (int gb = s; gb < e; gb += 64) {
        int active = min(64, e - gb);
        unsigned pkv = (lane < active) ? bkt[gb + lane] : 0u;
        int k = 0;
        for (; k + 8 <= active; k += 8) {
            unsigned pk0 = __builtin_amdgcn_readlane(pkv, k + 0);
            unsigned pk1 = __builtin_amdgcn_readlane(pkv, k + 1);
            unsigned pk2 = __builtin_amdgcn_readlane(pkv, k + 2);
            unsigned pk3 = __builtin_amdgcn_readlane(pkv, k + 3);
            unsigned pk4 = __builtin_amdgcn_readlane(pkv, k + 4);
            unsigned pk5 = __builtin_amdgcn_readlane(pkv, k + 5);
            unsigned pk6 = __builtin_amdgcn_readlane(pkv, k + 6);
            unsigned pk7 = __builtin_amdgcn_readlane(pkv, k + 7);
            float v0 = (float)Vp[(size_t)(pk0 >> 2) * 64 + lane];
            float v1 = (float)Vp[(size_t)(pk1 >> 2) * 64 + lane];
            float v2 = (float)Vp[(size_t)(pk2 >> 2) * 64 + lane];
            float v3 = (float)Vp[(size_t)(pk3 >> 2) * 64 + lane];
            float v4 = (float)Vp[(size_t)(pk4 >> 2) * 64 + lane];
            float v5 = (float)Vp[(size_t)(pk5 >> 2) * 64 + lane];
            float v6 = (float)Vp[(size_t)(pk6 >> 2) * 64 + lane];
            float v7 = (float)Vp[(size_t)(pk7 >> 2) * 64 + lane];
            int t0 = pk0 & 3, t1 = pk1 & 3, t2 = pk2 & 3, t3 = pk3 & 3;
            int t4 = pk4 & 3, t5 = pk5 & 3, t6 = pk6 & 3, t7 = pk7 & 3;
            acc0 += (t0 == 0) ? v0 : 0.f; acc1 += (t0 == 1) ? v0 : 0.f;
            acc2 += (t0 == 2) ? v0 : 0.f; acc3 += (t0 == 3) ? v0 : 0.f;
            acc0 += (t1 == 0) ? v1 : 0.f; acc1 += (t1 == 1) ? v1 : 0.f;
            acc2 += (t1 == 2) ? v1 : 0.f; acc3 += (t1 == 3) ? v1 : 0.f;
            acc0 += (t2 == 0) ? v2 : 0.f; acc1 += (t2 == 1) ? v2 : 0.f;
            acc2 += (t2 == 2) ? v2 : 0.f; acc3 += (t2 == 3) ? v2 : 0.f;
            acc0 += (t3 == 0) ? v3 : 0.f; acc1 += (t3 == 1) ? v3 : 0.f;
            acc2 += (t3 == 2) ? v3 : 0.f; acc3 += (t3 == 3) ? v3 : 0.f;
            acc0 += (t4 == 0) ? v4 : 0.f; acc1 += (t4 == 1) ? v4 : 0.f;
            acc2 += (t4 == 2) ? v4 : 0.f; acc3 += (t4 == 3) ? v4 : 0.f;
            acc0 += (t5 == 0) ? v5 : 0.f; acc1 += (t5 == 1) ? v5 : 0.f;
            acc2 += (t5 == 2) ? v5 : 0.f; acc3 += (t5 == 3) ? v5 : 0.f;
            acc0 += (t6 == 0) ? v6 : 0.f; acc1 += (t6 == 1) ? v6 : 0.f;
            acc2 += (t6 == 2) ? v6 : 0.f; acc3 += (t6 == 3) ? v6 : 0.f;
            acc0 += (t7 == 0) ? v7 : 0.f; acc1 += (t7 == 1) ? v7 : 0.f;
            acc2 += (t7 == 2) ? v7 : 0.f; acc3 += (t7 == 3) ? v7 : 0.f;
        }
        for (; k + 4 <= active; k += 4) {
            unsigned pk0 = __builtin_amdgcn_readlane(pkv, k + 0);
            unsigned pk1 = __builtin_amdgcn_readlane(pkv, k + 1);
            unsigned pk2 = __builtin_amdgcn_readlane(pkv, k + 2);
            unsigned pk3 = __builtin_amdgcn_readlane(pkv, k + 3);
            float v0 = (float)Vp[(size_t)(pk0 >> 2) * 64 + lane];
            float v1 = (float)Vp[(size_t)(pk1 >> 2) * 64 + lane];
            float v2 = (float)Vp[(size_t)(pk2 >> 2) * 64 + lane];
            float v3 = (float)Vp[(size_t)(pk3 >> 2) * 64 + lane];
            int t0 = pk0 & 3, t1 = pk1 & 3, t2 = pk2 & 3, t3 = pk3 & 3;
            acc0 += (t0 == 0) ? v0 : 0.f; acc1 += (t0 == 1) ? v0 : 0.f;
            acc2 += (t0 == 2) ? v0 : 0.f; acc3 += (t0 == 3) ? v0 : 0.f;
            acc0 += (t1 == 0) ? v1 : 0.f; acc1 += (t1 == 1) ? v1 : 0.f;
            acc2 += (t1 == 2) ? v1 : 0.f; acc3 += (t1 == 3) ? v1 : 0.f;
            acc0 += (t2 == 0) ? v2 : 0.f; acc1 += (t2 == 1) ? v2 : 0.f;
            acc2 += (t2 == 2) ? v2 : 0.f; acc3 += (t2 == 3) ? v2 : 0.f;
            acc0 += (t3 == 0) ? v3 : 0.f; acc1 += (t3 == 1) ? v3 : 0.f;
            acc2 += (t3 == 2) ? v3 : 0.f; acc3 += (t3 == 3) ? v3 : 0.f;
        }
        for (; k < active; ++k) {
            unsigned pk = __builtin_amdgcn_readlane(pkv, k);
            float v = (float)Vp[(size_t)(pk >> 2) * 64 + lane];
            int t = pk & 3;
            acc0 += (t == 0) ? v : 0.f; acc1 += (t == 1) ? v : 0.f;
            acc2 += (t == 2) ? v : 0.f; acc3 += (t == 3) ? v : 0.f;
        }
    }
    float d0 = dinv[c0 + 0], d1 = dinv[c0 + 1], d2 = dinv[c0 + 2], d3 = dinv[c0 + 3];
    float wv = wvec[lane];
    if constexpr (FINAL) {
        float* out = (float*)outv;
        out[(size_t)(c0 + 0) * 64 + lane] = acc0 * d0 + wv;
        out[(size_t)(c0 + 1) * 64 + lane] = acc1 * d1 + wv;
        out[(size_t)(c0 + 2) * 64 + lane] = acc2 * d2 + wv;
        out[(size_t)(c0 + 3) * 64 + lane] = acc3 * d3 + wv;
    } else {
        _Float16* out = (_Float16*)outv;
        out[(size_t)(c0 + 0) * 64 + lane] = (_Float16)(acc0 * d0 * d0 + d0 * wv);
        out[(size_t)(c0 + 1) * 64 + lane] = (_Float16)(acc1 * d1 * d1 + d1 * wv);
        out[(size_t)(c0 + 2) * 64 + lane] = (_Float16)(acc2 * d2 * d2 + d2 * wv);
        out[(size_t)(c0 + 3) * 64 + lane] = (_Float16)(acc3 * d3 * d3 + d3 * wv);
    }
}

// ---------------- launch ----------------

static inline size_t align256(size_t x) { return (x + 255) & ~(size_t)255; }

extern "C" void kernel_launch(void* const* d_in, const int* in_sizes, int n_in,
                              void* d_out, int out_size, void* d_ws, size_t ws_size,
                              hipStream_t stream) {
    const float* latent = (const float*)d_in[0];
    const float* cond   = (const float*)d_in[1];
    const int*   ei     = (const int*)d_in[2];
    const float* W1 = (const float*)d_in[3];
    const float* b1 = (const float*)d_in[4];
    const float* W2 = (const float*)d_in[5];
    const float* b2 = (const float*)d_in[6];
    const float* W3 = (const float*)d_in[7];
    const float* b3 = (const float*)d_in[8];
    const float* W4 = (const float*)d_in[9];
    const float* b4 = (const float*)d_in[10];
    float* out = (float*)d_out;

    const int N = in_sizes[0] / 64;          // 100000
    const int E = in_sizes[2] / 2;           // 1600000
    const int NB  = (N + BKN - 1) / BKN;     // 25000 fine buckets
    const int NCB = (N + CBN - 1) / CBN;     // 391 coarse bins
    const int NCH = (E + CHUNK - 1) / CHUNK; // 391 chunks

    // workspace layout
    char* w = (char*)d_ws;
    size_t o = 0;
    int* cntCB = (int*)(w + o); o = align256(o + (size_t)NCB * 4);
    int* offCB = (int*)(w + o); o = align256(o + (size_t)(NCB + 1) * 4);
    int* curCB = (int*)(w + o); o = align256(o + (size_t)NCB * 4);
    int* offB  = (int*)(w + o); o = align256(o + (size_t)(NB + 1) * 4);
    float* dinv = (float*)(w + o); o = align256(o + (size_t)N * 4);
    float* Wf1 = (float*)(w + o); o = align256(o + 4096 * 4);
    float* Wf2 = (float*)(w + o); o = align256(o + 2048 * 4);
    float* uVec = (float*)(w + o); o = align256(o + 64 * 4);
    float* vVec = (float*)(w + o); o = align256(o + 64 * 4);
    unsigned* binned = (unsigned*)(w + o); o = align256(o + (size_t)E * 4);
    unsigned* bkt    = (unsigned*)(w + o); o = align256(o + (size_t)E * 4);
    _Float16* Z = (_Float16*)(w + o); o = align256(o + (size_t)N * 64 * 2);
    _Float16* P = (_Float16*)(w + o); o = align256(o + (size_t)N * 64 * 2);

    const int BS = 256;
    int gHop = (NB + 3) / 4;   // 6250 blocks, 4 waves each

    // ---- build: 2-level counting sort; emits bkt, offB, dinv ----
    zero_int_kernel<<<2, BS, 0, stream>>>(cntCB, NCB);
    histCB_kernel<<<NCH, BS, 0, stream>>>(ei, cntCB, E, NCB);
    scanCB_kernel<<<1, 512, 0, stream>>>(cntCB, offCB, curCB, NCB);
    passA_kernel<<<NCH, BS, 0, stream>>>(ei, curCB, binned, E, NCB);
    passB_kernel<<<NCB, BS, 0, stream>>>(binned, offCB, bkt, offB, dinv, N, NCB, NB);

    // ---- weight fold + fused linear (MFMA) ----
    fold_kernel<<<1, BS, 0, stream>>>(W1, b1, W2, b2, W3, b3, W4, Wf1, Wf2, uVec, vVec);
    linZ_kernel<<<(N + 63) / 64, BS, 0, stream>>>(latent, cond, Wf1, Wf2, dinv, Z, N);

    // ---- three hops (u, v folded into epilogues; b4 at final) ----
    hop_kernel<false><<<gHop, BS, 0, stream>>>(Z, dinv, offB, bkt, uVec, (void*)P, NB);
    hop_kernel<false><<<gHop, BS, 0, stream>>>(P, dinv, offB, bkt, vVec, (void*)Z, NB);
    hop_kernel<true ><<<gHop, BS, 0, stream>>>(Z, dinv, offB, bkt, b4, (void*)out, NB);
}